// Round 1
// 501.278 us; speedup vs baseline: 1.0353x; 1.0353x over previous
//
#include <hip/hip_runtime.h>

// ---------------------------------------------------------------------------
// cosine_seqNet: out[b,o] = conv_b[o] + (1/6) * sum_{d,w} conv_w[o,d,w] *
//                 P[b,d,w],  P[b,d,w] = sum_{t=0..5} x[b,t+w,d]*cos[b,t+w]
// Shapes: B=256, S=10, D=4096, O=4096, W=5, K = D*W = 20480
// R4: (1) cos+build_p fused (one x pass + L2-warm rescale);
//     (2) GEMM: BK=64, double-buffered 2-phase pipeline (stage t+1 during
//         MFMA of t, ONE barrier/iter), 8-deep XOR LDS swizzle (conflict-free
//         ds_read_b128), split<->XCD affinity sp=bid&7 (A slice L2-resident).
// ---------------------------------------------------------------------------

#define BDIM 256
#define SEQ 10
#define DDIM 4096
#define ODIM 4096
#define WDIM 5
#define GK 20480               // D*W
#define SPLITS 8
#define KSPLIT (GK / SPLITS)   // 2560
#define BK 64
#define KITERS (KSPLIT / BK)   // 40

typedef __bf16 bf16x8 __attribute__((ext_vector_type(8)));
typedef float f32x4 __attribute__((ext_vector_type(4)));

__device__ __forceinline__ unsigned short f2bf(float f) {
    union { float f; unsigned v; } c; c.f = f;
    unsigned r = c.v + 0x7FFFu + ((c.v >> 16) & 1u);   // RNE
    return (unsigned short)(r >> 16);
}
__device__ __forceinline__ void async16(void* lds, const void* g) {
    __builtin_amdgcn_global_load_lds(
        (const __attribute__((address_space(1))) void*)g,
        (__attribute__((address_space(3))) void*)lds, 16, 0, 0);
}

// ---------------------------------------------------------------------------
// Kernel 1 (fused): cos[b,s] in shared, then P[b, d*5+w] = bf16(sum_t x*cos).
// One block per b. Phase 2 re-reads x[b] (163 KB) mostly from L1/L2;
// chunks walked in reverse so the hottest lines are hit first.
// ---------------------------------------------------------------------------
__global__ __launch_bounds__(256) void cosp_kernel(const float* __restrict__ x,
                                                   unsigned short* __restrict__ P)
{
    const int b = blockIdx.x;
    const int tid = threadIdx.x;
    const float* xb = x + (size_t)b * SEQ * DDIM;

    float dot[SEQ], sq[SEQ];
#pragma unroll
    for (int s = 0; s < SEQ; ++s) { dot[s] = 0.f; sq[s] = 0.f; }

    for (int base = 0; base < DDIM; base += 1024) {
        const int d = base + tid * 4;
        const f32x4 c4 = *(const f32x4*)(xb + 6 * DDIM + d);
#pragma unroll
        for (int s = 0; s < SEQ; ++s) {
            const f32x4 v4 = *(const f32x4*)(xb + s * DDIM + d);
            dot[s] += v4[0] * c4[0] + v4[1] * c4[1] + v4[2] * c4[2] + v4[3] * c4[3];
            sq[s]  += v4[0] * v4[0] + v4[1] * v4[1] + v4[2] * v4[2] + v4[3] * v4[3];
        }
    }
#pragma unroll
    for (int s = 0; s < SEQ; ++s) {
#pragma unroll
        for (int off = 32; off > 0; off >>= 1) {
            dot[s] += __shfl_down(dot[s], off, 64);
            sq[s]  += __shfl_down(sq[s], off, 64);
        }
    }
    __shared__ float red[4][2 * SEQ];
    __shared__ float cs[SEQ];
    const int wave = tid >> 6, lane = tid & 63;
    if (lane == 0) {
#pragma unroll
        for (int s = 0; s < SEQ; ++s) { red[wave][s] = dot[s]; red[wave][SEQ + s] = sq[s]; }
    }
    __syncthreads();
    if (tid == 0) {
        const float S6 = red[0][SEQ + 6] + red[1][SEQ + 6] + red[2][SEQ + 6] + red[3][SEQ + 6];
        const float cn = fmaxf(sqrtf(S6), 1e-8f);
#pragma unroll
        for (int s = 0; s < SEQ; ++s) {
            const float Dv = red[0][s] + red[1][s] + red[2][s] + red[3][s];
            const float Sv = red[0][SEQ + s] + red[1][SEQ + s] + red[2][SEQ + s] + red[3][SEQ + s];
            cs[s] = Dv / (fmaxf(sqrtf(Sv), 1e-8f) * cn);
        }
    }
    __syncthreads();

    float csr[SEQ];
#pragma unroll
    for (int s = 0; s < SEQ; ++s) csr[s] = cs[s];

    // Phase 2: P build, reverse chunk order (last-read chunks are cache-hot)
    for (int chunk = 3; chunk >= 0; --chunk) {
        const int d0 = chunk * 1024 + tid * 4;
        const float* xd = xb + d0;
        float sc[SEQ][4];
#pragma unroll
        for (int s = 0; s < SEQ; ++s) {
            const f32x4 v4 = *(const f32x4*)(xd + s * DDIM);
            sc[s][0] = v4[0] * csr[s]; sc[s][1] = v4[1] * csr[s];
            sc[s][2] = v4[2] * csr[s]; sc[s][3] = v4[3] * csr[s];
        }
        __attribute__((aligned(16))) unsigned short o[20];
#pragma unroll
        for (int w = 0; w < WDIM; ++w) {
#pragma unroll
            for (int j = 0; j < 4; ++j) {
                const float p = sc[w][j] + sc[w + 1][j] + sc[w + 2][j] +
                                sc[w + 3][j] + sc[w + 4][j] + sc[w + 5][j];
                o[j * WDIM + w] = f2bf(p);
            }
        }
        unsigned short* dst = P + ((size_t)b * DDIM + d0) * WDIM;
#pragma unroll
        for (int q = 0; q < 5; ++q)
            *(uint2*)(dst + q * 4) = *(const uint2*)(o + q * 4);
    }
}

// ---------------------------------------------------------------------------
// Kernel 2: split-K GEMM.  Cpart[sp,m,n] = sum_k A[m,k]*W[n,k]
// A = P bf16 (256 x 20480), W = conv_w fp32 (4096 x 20480) cvt'd at staging.
// Tile: 256(m) x 64(n), BK=64, double-buffered. 4 waves; wave w owns m rows
// [w*64, w*64+64), 4x4 frags of 16x16x32 MFMA, 2 k-halves per iter.
// LDS rows are 128 B: oct o of row r lives at phys oct o^(r&7)  (conflict-free
// ds_read_b128 per G4). A staged via global_load_lds with pre-swizzled global
// source (linear LDS dest); W staged global->reg->cvt->swizzled ds_write.
// 2-phase pipeline: stage tile t+1 (A async + W reg loads) BEFORE computing
// tile t; W cvt+ds_write after compute; single barrier per iteration.
// grid = 512 blocks: sp = bid&7 pins each split to one XCD (A slice 1.31 MB
// stays L2-resident; exactly 64 blocks = 2/CU on the XCD's 32 CUs).
// ---------------------------------------------------------------------------
__global__ __launch_bounds__(256, 2) void gemm_splitk_kernel(const unsigned short* __restrict__ A,
                                                             const float* __restrict__ W,
                                                             float* __restrict__ Cpart)
{
    const int bid = blockIdx.x;
    const int sp = bid & 7;       // split -> XCD affinity
    const int nt = bid >> 3;
    const int tid = threadIdx.x;
    const int lane = tid & 63;
    const int wave = tid >> 6;

    __shared__ __align__(16) unsigned short lds_a[2][256 * BK];  // 2 x 32 KB
    __shared__ __align__(16) unsigned short lds_w[2][64 * BK];   // 2 x  8 KB

    f32x4 acc[4][4];
#pragma unroll
    for (int i = 0; i < 4; ++i)
#pragma unroll
        for (int j = 0; j < 4; ++j)
            acc[i][j] = (f32x4){0.f, 0.f, 0.f, 0.f};

    // ---- A staging geometry: 8 async16/thread; chunk q = 32 rows (4096 B).
    // dest byte = q*4096 + tid*16  ->  row q*32 + (tid>>3), phys oct tid&7.
    // global source column oct = phys ^ (row&7)  (inverse swizzle, m173).
    const int s_arow = tid >> 3;       // 0..31
    const int s_aoct = tid & 7;

    // ---- W staging geometry: row tid>>2 (0..63), 16 floats at col (tid&3)*16.
    const int s_wrow = tid >> 2;
    const float* wsrc = W + ((size_t)(nt * 64 + s_wrow)) * GK + (tid & 3) * 16;
    const int wo0 = (((tid & 3) * 2)     ^ (s_wrow & 7)) * 8;  // phys elem off
    const int wo1 = (((tid & 3) * 2 + 1) ^ (s_wrow & 7)) * 8;

    // ---- fragment read offsets (elements), [kh][i]; swizzled
    const int fm = lane & 15;          // n (W) / m (A) within 16
    const int fg = lane >> 4;          // k-oct group 0..3
    int aoff[2][4], woff[2][4];
#pragma unroll
    for (int i = 0; i < 4; ++i) {
        const int ra = wave * 64 + i * 16 + fm;
        const int rw = i * 16 + fm;
#pragma unroll
        for (int kh = 0; kh < 2; ++kh) {
            aoff[kh][i] = ra * BK + (((kh * 4 + fg) ^ (ra & 7)) * 8);
            woff[kh][i] = rw * BK + (((kh * 4 + fg) ^ (rw & 7)) * 8);
        }
    }

#define STAGE_A(buf, kk)                                                        \
    _Pragma("unroll")                                                           \
    for (int q = 0; q < 8; ++q) {                                               \
        const int row_ = q * 32 + s_arow;                                       \
        const unsigned short* src_ =                                            \
            A + (size_t)row_ * GK + (kk) + ((s_aoct ^ (row_ & 7)) * 8);         \
        async16((char*)&lds_a[buf][0] + q * 4096 + tid * 16, src_);             \
    }

#define LOAD_W(kk)                                                              \
    w0 = *(const f32x4*)(wsrc + (kk));                                          \
    w1 = *(const f32x4*)(wsrc + (kk) + 4);                                      \
    w2 = *(const f32x4*)(wsrc + (kk) + 8);                                      \
    w3 = *(const f32x4*)(wsrc + (kk) + 12);

#define WRITE_W(buf)                                                            \
    {                                                                           \
        bf16x8 lo_, hi_;                                                        \
        _Pragma("unroll")                                                       \
        for (int e = 0; e < 4; ++e) {                                           \
            lo_[e] = (__bf16)w0[e]; lo_[4 + e] = (__bf16)w1[e];                 \
            hi_[e] = (__bf16)w2[e]; hi_[4 + e] = (__bf16)w3[e];                 \
        }                                                                       \
        *(bf16x8*)&lds_w[buf][s_wrow * BK + wo0] = lo_;                         \
        *(bf16x8*)&lds_w[buf][s_wrow * BK + wo1] = hi_;                         \
    }

#define COMPUTE(buf)                                                            \
    _Pragma("unroll")                                                           \
    for (int kh = 0; kh < 2; ++kh) {                                            \
        bf16x8 af[4], wf[4];                                                    \
        _Pragma("unroll")                                                       \
        for (int i = 0; i < 4; ++i) af[i] = *(const bf16x8*)&lds_a[buf][aoff[kh][i]]; \
        _Pragma("unroll")                                                       \
        for (int j = 0; j < 4; ++j) wf[j] = *(const bf16x8*)&lds_w[buf][woff[kh][j]]; \
        _Pragma("unroll")                                                       \
        for (int i = 0; i < 4; ++i)                                             \
            _Pragma("unroll")                                                   \
            for (int j = 0; j < 4; ++j)                                         \
                acc[i][j] = __builtin_amdgcn_mfma_f32_16x16x32_bf16(            \
                    af[i], wf[j], acc[i][j], 0, 0, 0);                          \
    }

    int k0 = sp * KSPLIT;
    f32x4 w0, w1, w2, w3;

    // prologue: fill buffer 0 (compiler drains vmcnt(0) before the barrier)
    STAGE_A(0, k0);
    LOAD_W(k0);
    WRITE_W(0);
    __syncthreads();

    // steady state: ONE barrier per iteration; loads for t+1 fly during MFMA(t)
    for (int it = 0; it < KITERS - 1; ++it) {
        const int cur = it & 1, nxt = cur ^ 1;
        STAGE_A(nxt, k0 + BK);     // async global->LDS (next tile)
        LOAD_W(k0 + BK);           // fp32 W -> regs (next tile)
        COMPUTE(cur);              // ds_read + 32 MFMA, hides the loads
        WRITE_W(nxt);              // cvt+ds_write after loads landed
        __syncthreads();
        k0 += BK;
    }
    COMPUTE((KITERS - 1) & 1);     // tail: no staging

    // C/D layout: col(n) = lane&15, row(m) = (lane>>4)*4 + reg  [m89-verified]
    float* Cp = Cpart + (size_t)sp * (BDIM * ODIM);
    const int mbase = wave * 64 + fg * 4;
    const int nbase = nt * 64 + fm;
#pragma unroll
    for (int i = 0; i < 4; ++i)
#pragma unroll
        for (int j = 0; j < 4; ++j) {
            const int n = nbase + j * 16;
#pragma unroll
            for (int r = 0; r < 4; ++r) {
                const int m = mbase + i * 16 + r;
                Cp[(size_t)m * ODIM + n] = acc[i][j][r];
            }
        }
#undef STAGE_A
#undef LOAD_W
#undef WRITE_W
#undef COMPUTE
}

// ---------------------------------------------------------------------------
// Kernel 3: out[b,o] = sum_sp partial[sp,b,o] / 6 + conv_b[o]
// ---------------------------------------------------------------------------
__global__ __launch_bounds__(256) void reduce_kernel(const float* __restrict__ part,
                                                     const float* __restrict__ bias,
                                                     float* __restrict__ out)
{
    const int idx = (blockIdx.x * 256 + threadIdx.x) * 4;
    f32x4 s = (f32x4){0.f, 0.f, 0.f, 0.f};
#pragma unroll
    for (int sp = 0; sp < SPLITS; ++sp) {
        const f32x4 v = *(const f32x4*)(part + (size_t)sp * (BDIM * ODIM) + idx);
        s[0] += v[0]; s[1] += v[1]; s[2] += v[2]; s[3] += v[3];
    }
    const int n = idx & (ODIM - 1);
    const f32x4 b4 = *(const f32x4*)(bias + n);
    const float inv6 = 1.0f / 6.0f;
    f32x4 o;
#pragma unroll
    for (int e = 0; e < 4; ++e) o[e] = s[e] * inv6 + b4[e];
    *(f32x4*)(out + idx) = o;
}

// ---------------------------------------------------------------------------
extern "C" void kernel_launch(void* const* d_in, const int* in_sizes, int n_in,
                              void* d_out, int out_size, void* d_ws, size_t ws_size,
                              hipStream_t stream) {
    const float* x  = (const float*)d_in[0];   // fp32 (256,10,4096)
    const float* cw = (const float*)d_in[1];   // fp32 (4096,4096,5)
    const float* cb = (const float*)d_in[2];   // fp32 (4096,)
    float* out = (float*)d_out;                // fp32 (256,4096)

    char* ws = (char*)d_ws;
    unsigned short* P = (unsigned short*)(ws + 16384);               // 10.49 MB bf16
    float* parts = (float*)(ws + 16384 + (size_t)BDIM * GK * 2);     // 33.55 MB fp32

    hipLaunchKernelGGL(cosp_kernel,        dim3(256),  dim3(256), 0, stream, x, P);
    hipLaunchKernelGGL(gemm_splitk_kernel, dim3(512),  dim3(256), 0, stream, P, cw, parts);
    hipLaunchKernelGGL(reduce_kernel,      dim3(1024), dim3(256), 0, stream, parts, cb, out);
}

// Round 2
// 493.252 us; speedup vs baseline: 1.0521x; 1.0163x over previous
//
#include <hip/hip_runtime.h>

// ---------------------------------------------------------------------------
// cosine_seqNet: out[b,o] = conv_b[o] + (1/6) * sum_{d,w} conv_w[o,d,w] *
//                 P[b,d,w],  P[b,d,w] = sum_{t=0..5} x[b,t+w,d]*cos[b,t+w]
// Shapes: B=256, S=10, D=4096, O=4096, W=5, K = D*W = 20480
// R5: GEMM is HBM-bound on the W fp32 stream (335.5 MB -> 53 us floor).
//     Replaced __syncthreads (vmcnt(0) drain) with raw s_barrier + COUNTED
//     vmcnt waits (T3/T4): A staged 1 iter ahead via global_load_lds and
//     waited with vmcnt(12) at COMPUTE start; W prefetched 2 iters ahead
//     into alternating static reg sets, cvt+ds_write after COMPUTE,
//     lgkmcnt(0)+s_barrier. Loop unrolled x2 so all indices are static.
// ---------------------------------------------------------------------------

#define BDIM 256
#define SEQ 10
#define DDIM 4096
#define ODIM 4096
#define WDIM 5
#define GK 20480               // D*W
#define SPLITS 8
#define KSPLIT (GK / SPLITS)   // 2560
#define BK 64
#define KITERS (KSPLIT / BK)   // 40

typedef __bf16 bf16x8 __attribute__((ext_vector_type(8)));
typedef float f32x4 __attribute__((ext_vector_type(4)));

__device__ __forceinline__ unsigned short f2bf(float f) {
    union { float f; unsigned v; } c; c.f = f;
    unsigned r = c.v + 0x7FFFu + ((c.v >> 16) & 1u);   // RNE
    return (unsigned short)(r >> 16);
}
__device__ __forceinline__ void async16(void* lds, const void* g) {
    __builtin_amdgcn_global_load_lds(
        (const __attribute__((address_space(1))) void*)g,
        (__attribute__((address_space(3))) void*)lds, 16, 0, 0);
}

#define VMWAIT(n) asm volatile("s_waitcnt vmcnt(" #n ")" ::: "memory")
#define LGKM0()   asm volatile("s_waitcnt lgkmcnt(0)" ::: "memory")
#define SBAR()    __builtin_amdgcn_s_barrier()
#define SCHED0()  __builtin_amdgcn_sched_barrier(0)

// ---------------------------------------------------------------------------
// Kernel 1 (fused): cos[b,s] in shared, then P[b, d*5+w] = bf16(sum_t x*cos).
// ---------------------------------------------------------------------------
__global__ __launch_bounds__(256) void cosp_kernel(const float* __restrict__ x,
                                                   unsigned short* __restrict__ P)
{
    const int b = blockIdx.x;
    const int tid = threadIdx.x;
    const float* xb = x + (size_t)b * SEQ * DDIM;

    float dot[SEQ], sq[SEQ];
#pragma unroll
    for (int s = 0; s < SEQ; ++s) { dot[s] = 0.f; sq[s] = 0.f; }

    for (int base = 0; base < DDIM; base += 1024) {
        const int d = base + tid * 4;
        const f32x4 c4 = *(const f32x4*)(xb + 6 * DDIM + d);
#pragma unroll
        for (int s = 0; s < SEQ; ++s) {
            const f32x4 v4 = *(const f32x4*)(xb + s * DDIM + d);
            dot[s] += v4[0] * c4[0] + v4[1] * c4[1] + v4[2] * c4[2] + v4[3] * c4[3];
            sq[s]  += v4[0] * v4[0] + v4[1] * v4[1] + v4[2] * v4[2] + v4[3] * v4[3];
        }
    }
#pragma unroll
    for (int s = 0; s < SEQ; ++s) {
#pragma unroll
        for (int off = 32; off > 0; off >>= 1) {
            dot[s] += __shfl_down(dot[s], off, 64);
            sq[s]  += __shfl_down(sq[s], off, 64);
        }
    }
    __shared__ float red[4][2 * SEQ];
    __shared__ float cs[SEQ];
    const int wave = tid >> 6, lane = tid & 63;
    if (lane == 0) {
#pragma unroll
        for (int s = 0; s < SEQ; ++s) { red[wave][s] = dot[s]; red[wave][SEQ + s] = sq[s]; }
    }
    __syncthreads();
    if (tid == 0) {
        const float S6 = red[0][SEQ + 6] + red[1][SEQ + 6] + red[2][SEQ + 6] + red[3][SEQ + 6];
        const float cn = fmaxf(sqrtf(S6), 1e-8f);
#pragma unroll
        for (int s = 0; s < SEQ; ++s) {
            const float Dv = red[0][s] + red[1][s] + red[2][s] + red[3][s];
            const float Sv = red[0][SEQ + s] + red[1][SEQ + s] + red[2][SEQ + s] + red[3][SEQ + s];
            cs[s] = Dv / (fmaxf(sqrtf(Sv), 1e-8f) * cn);
        }
    }
    __syncthreads();

    float csr[SEQ];
#pragma unroll
    for (int s = 0; s < SEQ; ++s) csr[s] = cs[s];

    for (int chunk = 3; chunk >= 0; --chunk) {
        const int d0 = chunk * 1024 + tid * 4;
        const float* xd = xb + d0;
        float sc[SEQ][4];
#pragma unroll
        for (int s = 0; s < SEQ; ++s) {
            const f32x4 v4 = *(const f32x4*)(xd + s * DDIM);
            sc[s][0] = v4[0] * csr[s]; sc[s][1] = v4[1] * csr[s];
            sc[s][2] = v4[2] * csr[s]; sc[s][3] = v4[3] * csr[s];
        }
        __attribute__((aligned(16))) unsigned short o[20];
#pragma unroll
        for (int w = 0; w < WDIM; ++w) {
#pragma unroll
            for (int j = 0; j < 4; ++j) {
                const float p = sc[w][j] + sc[w + 1][j] + sc[w + 2][j] +
                                sc[w + 3][j] + sc[w + 4][j] + sc[w + 5][j];
                o[j * WDIM + w] = f2bf(p);
            }
        }
        unsigned short* dst = P + ((size_t)b * DDIM + d0) * WDIM;
#pragma unroll
        for (int q = 0; q < 5; ++q)
            *(uint2*)(dst + q * 4) = *(const uint2*)(o + q * 4);
    }
}

// ---------------------------------------------------------------------------
// Kernel 2: split-K GEMM, counted-vmcnt pipeline (see header comment).
// Tile 256(m) x 64(n), BK=64, A dbuf (global_load_lds, pre-swizzled source),
// W 2-iter-ahead reg prefetch + swizzled ds_write. Raw s_barrier; per-iter
// vmem = 8 async16 + 4 dwordx4 = 12 -> steady-state wait is vmcnt(12).
// ---------------------------------------------------------------------------
__global__ __launch_bounds__(256, 2) void gemm_splitk_kernel(const unsigned short* __restrict__ A,
                                                             const float* __restrict__ W,
                                                             float* __restrict__ Cpart)
{
    const int bid = blockIdx.x;
    const int sp = bid & 7;       // split -> XCD affinity (A slice L2-resident)
    const int nt = bid >> 3;
    const int tid = threadIdx.x;
    const int lane = tid & 63;
    const int wave = tid >> 6;

    __shared__ __align__(16) unsigned short lds_a[2][256 * BK];  // 2 x 32 KB
    __shared__ __align__(16) unsigned short lds_w[2][64 * BK];   // 2 x  8 KB

    f32x4 acc[4][4];
#pragma unroll
    for (int i = 0; i < 4; ++i)
#pragma unroll
        for (int j = 0; j < 4; ++j)
            acc[i][j] = (f32x4){0.f, 0.f, 0.f, 0.f};

    // A staging: 8 async16/thread; dest = q*4096 + tid*16 (linear);
    // source column oct pre-swizzled: oct = (tid&7) ^ (row&7).
    const int s_arow = tid >> 3;       // 0..31
    const int s_aoct = tid & 7;

    // W staging: row tid>>2 (0..63), 16 floats at col (tid&3)*16.
    const int s_wrow = tid >> 2;
    const float* wsrc = W + ((size_t)(nt * 64 + s_wrow)) * GK + (tid & 3) * 16;
    const int wo0 = (((tid & 3) * 2)     ^ (s_wrow & 7)) * 8;
    const int wo1 = (((tid & 3) * 2 + 1) ^ (s_wrow & 7)) * 8;

    // fragment read offsets (elements), [kh][i]; swizzled
    const int fm = lane & 15;
    const int fg = lane >> 4;
    int aoff[2][4], woff[2][4];
#pragma unroll
    for (int i = 0; i < 4; ++i) {
        const int ra = wave * 64 + i * 16 + fm;
        const int rw = i * 16 + fm;
#pragma unroll
        for (int kh = 0; kh < 2; ++kh) {
            aoff[kh][i] = ra * BK + (((kh * 4 + fg) ^ (ra & 7)) * 8);
            woff[kh][i] = rw * BK + (((kh * 4 + fg) ^ (rw & 7)) * 8);
        }
    }

#define STAGE_A(buf, kk)                                                        \
    _Pragma("unroll")                                                           \
    for (int q = 0; q < 8; ++q) {                                               \
        const int row_ = q * 32 + s_arow;                                       \
        const unsigned short* src_ =                                            \
            A + (size_t)row_ * GK + (kk) + ((s_aoct ^ (row_ & 7)) * 8);         \
        async16((char*)&lds_a[buf][0] + q * 4096 + tid * 16, src_);             \
    }

#define LOAD_W(R0, R1, R2, R3, kk)                                              \
    R0 = *(const f32x4*)(wsrc + (kk));                                          \
    R1 = *(const f32x4*)(wsrc + (kk) + 4);                                      \
    R2 = *(const f32x4*)(wsrc + (kk) + 8);                                      \
    R3 = *(const f32x4*)(wsrc + (kk) + 12);

#define WRITE_W(buf, R0, R1, R2, R3)                                            \
    {                                                                           \
        bf16x8 lo_, hi_;                                                        \
        _Pragma("unroll")                                                       \
        for (int e = 0; e < 4; ++e) {                                           \
            lo_[e] = (__bf16)R0[e]; lo_[4 + e] = (__bf16)R1[e];                 \
            hi_[e] = (__bf16)R2[e]; hi_[4 + e] = (__bf16)R3[e];                 \
        }                                                                       \
        *(bf16x8*)&lds_w[buf][s_wrow * BK + wo0] = lo_;                         \
        *(bf16x8*)&lds_w[buf][s_wrow * BK + wo1] = hi_;                         \
    }

#define COMPUTE(buf)                                                            \
    _Pragma("unroll")                                                           \
    for (int kh = 0; kh < 2; ++kh) {                                            \
        bf16x8 af[4], wf[4];                                                    \
        _Pragma("unroll")                                                       \
        for (int i = 0; i < 4; ++i) af[i] = *(const bf16x8*)&lds_a[buf][aoff[kh][i]]; \
        _Pragma("unroll")                                                       \
        for (int j = 0; j < 4; ++j) wf[j] = *(const bf16x8*)&lds_w[buf][woff[kh][j]]; \
        _Pragma("unroll")                                                       \
        for (int i = 0; i < 4; ++i)                                             \
            _Pragma("unroll")                                                   \
            for (int j = 0; j < 4; ++j)                                         \
                acc[i][j] = __builtin_amdgcn_mfma_f32_16x16x32_bf16(            \
                    af[i], wf[j], acc[i][j], 0, 0, 0);                          \
    }

    const int ksp = sp * KSPLIT;
    f32x4 wA0, wA1, wA2, wA3;   // reg set A (even-iter loads)
    f32x4 wB0, wB1, wB2, wB3;   // reg set B (odd-iter loads)

    // ---- prologue: W(0)->setA, A(0)->buf0, W(0)->LDS, W(1)->setB ----------
    LOAD_W(wA0, wA1, wA2, wA3, ksp);           // 4 vmem
    STAGE_A(0, ksp);                           // 8 vmem
    VMWAIT(8); SCHED0();                       // W(0) regs landed
    WRITE_W(0, wA0, wA1, wA2, wA3);
    LOAD_W(wB0, wB1, wB2, wB3, ksp + BK);      // W(1), 4 vmem
    VMWAIT(4); SCHED0();                       // A(0) landed (W(1) may fly)
    LGKM0();
    SBAR(); SCHED0();

    int kbase = ksp;
    // ---- steady state: t = 0..37, unrolled x2 (static bufs/reg sets) ------
    for (int tt = 0; tt < (KITERS - 2) / 2; ++tt) {
        // t even: cur buf0, stage buf1, load W(t+2)->setA, write W(t+1) from setB
        SCHED0();
        STAGE_A(1, kbase + BK);
        LOAD_W(wA0, wA1, wA2, wA3, kbase + 2 * BK);
        VMWAIT(12); SCHED0();                  // A(t), W(t+1) landed
        COMPUTE(0);
        WRITE_W(1, wB0, wB1, wB2, wB3);
        LGKM0();
        SBAR(); SCHED0();
        kbase += BK;
        // t odd: cur buf1, stage buf0, load W(t+2)->setB, write W(t+1) from setA
        STAGE_A(0, kbase + BK);
        LOAD_W(wB0, wB1, wB2, wB3, kbase + 2 * BK);
        VMWAIT(12); SCHED0();
        COMPUTE(1);
        WRITE_W(0, wA0, wA1, wA2, wA3);
        LGKM0();
        SBAR(); SCHED0();
        kbase += BK;
    }
    // ---- tail t = 38 (even): stage A(39); W(39) already in setB -----------
    STAGE_A(1, kbase + BK);
    VMWAIT(8); SCHED0();                       // A(38), W(39) landed
    COMPUTE(0);
    WRITE_W(1, wB0, wB1, wB2, wB3);
    LGKM0();
    SBAR(); SCHED0();
    // ---- tail t = 39 (odd) ------------------------------------------------
    VMWAIT(0); SCHED0();                       // A(39) landed
    COMPUTE(1);

    // C/D layout: col(n) = lane&15, row(m) = (lane>>4)*4 + reg  [m89-verified]
    float* Cp = Cpart + (size_t)sp * (BDIM * ODIM);
    const int mbase = wave * 64 + fg * 4;
    const int nbase = nt * 64 + fm;
#pragma unroll
    for (int i = 0; i < 4; ++i)
#pragma unroll
        for (int j = 0; j < 4; ++j) {
            const int n = nbase + j * 16;
#pragma unroll
            for (int r = 0; r < 4; ++r) {
                const int m = mbase + i * 16 + r;
                Cp[(size_t)m * ODIM + n] = acc[i][j][r];
            }
        }
#undef STAGE_A
#undef LOAD_W
#undef WRITE_W
#undef COMPUTE
}

// ---------------------------------------------------------------------------
// Kernel 3: out[b,o] = sum_sp partial[sp,b,o] / 6 + conv_b[o]
// ---------------------------------------------------------------------------
__global__ __launch_bounds__(256) void reduce_kernel(const float* __restrict__ part,
                                                     const float* __restrict__ bias,
                                                     float* __restrict__ out)
{
    const int idx = (blockIdx.x * 256 + threadIdx.x) * 4;
    f32x4 s = (f32x4){0.f, 0.f, 0.f, 0.f};
#pragma unroll
    for (int sp = 0; sp < SPLITS; ++sp) {
        const f32x4 v = *(const f32x4*)(part + (size_t)sp * (BDIM * ODIM) + idx);
        s[0] += v[0]; s[1] += v[1]; s[2] += v[2]; s[3] += v[3];
    }
    const int n = idx & (ODIM - 1);
    const f32x4 b4 = *(const f32x4*)(bias + n);
    const float inv6 = 1.0f / 6.0f;
    f32x4 o;
#pragma unroll
    for (int e = 0; e < 4; ++e) o[e] = s[e] * inv6 + b4[e];
    *(f32x4*)(out + idx) = o;
}

// ---------------------------------------------------------------------------
extern "C" void kernel_launch(void* const* d_in, const int* in_sizes, int n_in,
                              void* d_out, int out_size, void* d_ws, size_t ws_size,
                              hipStream_t stream) {
    const float* x  = (const float*)d_in[0];   // fp32 (256,10,4096)
    const float* cw = (const float*)d_in[1];   // fp32 (4096,4096,5)
    const float* cb = (const float*)d_in[2];   // fp32 (4096,)
    float* out = (float*)d_out;                // fp32 (256,4096)

    char* ws = (char*)d_ws;
    unsigned short* P = (unsigned short*)(ws + 16384);               // 10.49 MB bf16
    float* parts = (float*)(ws + 16384 + (size_t)BDIM * GK * 2);     // 33.55 MB fp32

    hipLaunchKernelGGL(cosp_kernel,        dim3(256),  dim3(256), 0, stream, x, P);
    hipLaunchKernelGGL(gemm_splitk_kernel, dim3(512),  dim3(256), 0, stream, P, cw, parts);
    hipLaunchKernelGGL(reduce_kernel,      dim3(1024), dim3(256), 0, stream, parts, cb, out);
}